// Round 1
// baseline (1027.390 us; speedup 1.0000x reference)
//
#include <hip/hip_runtime.h>

typedef _Float16 f16;
typedef _Float16 f16x8 __attribute__((ext_vector_type(8)));
typedef float f32x4 __attribute__((ext_vector_type(4)));

#define MFMA16(a,b,c) __builtin_amdgcn_mfma_f32_16x16x32_f16((a),(b),(c),0,0,0)

// ---------------- index dtype detection + normalization ----------------
__global__ void k_detect(const long long* ei, int n_nodes, int* flag) {
    if (blockIdx.x == 0 && threadIdx.x == 0) {
        int ok = 1;
        for (int i = 0; i < 64; i++) {
            long long v = ei[i];
            if (v < 0 || v >= n_nodes) { ok = 0; break; }
        }
        *flag = ok;   // 1 => buffer is int64, 0 => int32
    }
}

__global__ void k_idx(const void* ei, int E, const int* __restrict__ flag,
                      int* __restrict__ src, int* __restrict__ dst) {
    int e = blockIdx.x * 256 + threadIdx.x;
    if (e >= E) return;
    if (*flag) {
        const long long* p = (const long long*)ei;
        src[e] = (int)p[e];
        dst[e] = (int)p[(size_t)E + e];
    } else {
        const int* p = (const int*)ei;
        src[e] = p[e];
        dst[e] = p[(size_t)E + e];
    }
}

// ---------------- fp32 -> fp16 convert (x table) ----------------
__global__ void k_x2h(const float* __restrict__ x, f16* __restrict__ xh, int n) {
    int i = (blockIdx.x * 256 + threadIdx.x) * 8;
    if (i >= n) return;
    float4 a = *(const float4*)(x + i);
    float4 b = *(const float4*)(x + i + 4);
    f16x8 h;
    h[0] = (f16)a.x; h[1] = (f16)a.y; h[2] = (f16)a.z; h[3] = (f16)a.w;
    h[4] = (f16)b.x; h[5] = (f16)b.y; h[6] = (f16)b.z; h[7] = (f16)b.w;
    *(f16x8*)(xh + i) = h;
}

// ---------------- W -> fp16 frag-ordered ----------------
// dst layout: halfs at ((s*8+ct)*64+lane)*8 + e  where B[k][j], k=32s+8*(lane>>4)+e, j=16ct+(lane&15)
// Wb != null: k<128 -> Wa[k][j], else Wb[k-128][j]   (SAGE, KS=8)
// Wb == null: k<272 -> Wa[k][j], else 0              (edge MLP, KS=9)
__global__ void k_wfrag(const float* __restrict__ Wa, const float* __restrict__ Wb,
                        f16* __restrict__ dst, int KS) {
    int t = blockIdx.x * 256 + threadIdx.x;
    int total = KS * 8 * 64;
    if (t >= total) return;
    int l = t & 63;
    int s = t >> 9;
    int k0 = s * 32 + (l >> 4) * 8;
    int j = ((t >> 6) & 7) * 16 + (l & 15);
    f16x8 h;
    #pragma unroll
    for (int e = 0; e < 8; e++) {
        int k = k0 + e;
        float v;
        if (Wb) v = (k < 128) ? Wa[k * 128 + j] : Wb[(k - 128) * 128 + j];
        else    v = (k < 272) ? Wa[k * 128 + j] : 0.0f;
        h[e] = (f16)v;
    }
    *(f16x8*)(dst + (size_t)t * 8) = h;
}

// ---------------- CSR build ----------------
__global__ void k_hist(const int* __restrict__ dst, int E, int* __restrict__ deg) {
    int e = blockIdx.x * 256 + threadIdx.x;
    if (e < E) atomicAdd(&deg[dst[e]], 1);
}

__global__ void k_scan(const int* __restrict__ deg, int n,
                       int* __restrict__ rowptr, int* __restrict__ cursor) {
    __shared__ int wsum[16];
    const int tid = threadIdx.x, lane = tid & 63, wid = tid >> 6;
    int carry = 0;
    for (int base = 0; base < n; base += 4096) {
        int i = base + tid * 4;
        int d0 = (i     < n) ? deg[i]     : 0;
        int d1 = (i + 1 < n) ? deg[i + 1] : 0;
        int d2 = (i + 2 < n) ? deg[i + 2] : 0;
        int d3 = (i + 3 < n) ? deg[i + 3] : 0;
        int s = d0 + d1 + d2 + d3;
        int inc = s;
        #pragma unroll
        for (int off = 1; off < 64; off <<= 1) {
            int u = __shfl_up(inc, off, 64);
            if (lane >= off) inc += u;
        }
        if (lane == 63) wsum[wid] = inc;
        __syncthreads();
        if (tid < 16) {
            int v = wsum[tid];
            #pragma unroll
            for (int off = 1; off < 16; off <<= 1) {
                int u = __shfl_up(v, off, 64);
                if (tid >= off) v += u;
            }
            wsum[tid] = v;
        }
        __syncthreads();
        int woff = (wid == 0) ? 0 : wsum[wid - 1];
        int excl = carry + woff + (inc - s);
        int e1 = excl + d0, e2 = e1 + d1, e3 = e2 + d2;
        if (i     < n) { rowptr[i]     = excl; cursor[i]     = excl; }
        if (i + 1 < n) { rowptr[i + 1] = e1;   cursor[i + 1] = e1; }
        if (i + 2 < n) { rowptr[i + 2] = e2;   cursor[i + 2] = e2; }
        if (i + 3 < n) { rowptr[i + 3] = e3;   cursor[i + 3] = e3; }
        carry += wsum[15];
        __syncthreads();
    }
    if (tid == 0) rowptr[n] = carry;
}

__global__ void k_scatter(const int* __restrict__ src, const int* __restrict__ dst, int E,
                          int* __restrict__ cursor, int* __restrict__ col) {
    int e = blockIdx.x * 256 + threadIdx.x;
    if (e < E) {
        int p = atomicAdd(&cursor[dst[e]], 1);
        col[p] = src[e];
    }
}

// ---------------- mean aggregation: one wave per node ----------------
__global__ void k_agg(const f16* __restrict__ tab, const int* __restrict__ rowptr,
                      const int* __restrict__ col, f16* __restrict__ mean, int n_nodes) {
    const int gw = (int)((blockIdx.x * (unsigned)blockDim.x + threadIdx.x) >> 6);
    const int lane = threadIdx.x & 63;
    if (gw >= n_nodes) return;
    const int s0 = rowptr[gw], s1 = rowptr[gw + 1];
    float a0 = 0.f, a1 = 0.f;
    int k = s0;
    for (; k + 1 < s1; k += 2) {
        const int n0 = col[k], n1 = col[k + 1];
        union { unsigned int u; f16 h[2]; } u0, u1;
        u0.u = *(const unsigned int*)(tab + (size_t)n0 * 128 + lane * 2);
        u1.u = *(const unsigned int*)(tab + (size_t)n1 * 128 + lane * 2);
        a0 += (float)u0.h[0] + (float)u1.h[0];
        a1 += (float)u0.h[1] + (float)u1.h[1];
    }
    if (k < s1) {
        const int n0 = col[k];
        union { unsigned int u; f16 h[2]; } u0;
        u0.u = *(const unsigned int*)(tab + (size_t)n0 * 128 + lane * 2);
        a0 += (float)u0.h[0];
        a1 += (float)u0.h[1];
    }
    int d = s1 - s0; if (d < 1) d = 1;
    const float inv = 1.f / (float)d;
    union { unsigned int u; f16 h[2]; } r;
    r.h[0] = (f16)(a0 * inv);
    r.h[1] = (f16)(a1 * inv);
    *(unsigned int*)(mean + (size_t)gw * 128 + lane * 2) = r.u;
}

// ---------------- SAGE GEMM: h = relu([A1|A2] @ W + b), fp16 MFMA ----------------
__global__ __launch_bounds__(256, 2) void k_gemm_sage(
    const f16* __restrict__ A1, const f16* __restrict__ A2,
    const f16* __restrict__ Wf, const float* __restrict__ bias,
    f16* __restrict__ out, int n_rows, int iters, int gridW) {
    __shared__ __align__(16) f16 sW[8 * 8 * 64 * 8];
    const int tid = threadIdx.x, lane = tid & 63, w = tid >> 6;
    const int l15 = lane & 15, g = lane >> 4;
    for (int i = tid; i < 8 * 8 * 64; i += 256)
        *(uint4*)&sW[(size_t)i * 8] = *(const uint4*)&Wf[(size_t)i * 8];
    __syncthreads();
    const int c0 = (2 * w) * 16 + l15, c1 = (2 * w + 1) * 16 + l15;
    const float b0 = bias[c0], b1 = bias[c1];
    for (int it = 0; it < iters; ++it) {
        const int base = (blockIdx.x + it * gridW) * 64;
        if (base >= n_rows) break;
        f32x4 acc[4][2];
        #pragma unroll
        for (int t = 0; t < 4; t++) {
            acc[t][0] = f32x4{b0, b0, b0, b0};
            acc[t][1] = f32x4{b1, b1, b1, b1};
        }
        #pragma unroll
        for (int s = 0; s < 8; s++) {
            const f16* Asrc = (s < 4) ? A1 : A2;
            const int koff = (s & 3) * 32 + g * 8;
            f16x8 bf0 = *(const f16x8*)&sW[((s * 8 + 2 * w    ) * 64 + lane) * 8];
            f16x8 bf1 = *(const f16x8*)&sW[((s * 8 + 2 * w + 1) * 64 + lane) * 8];
            #pragma unroll
            for (int t = 0; t < 4; t++) {
                int row = base + t * 16 + l15;
                if (row >= n_rows) row = n_rows - 1;
                f16x8 a = *(const f16x8*)(Asrc + (size_t)row * 128 + koff);
                acc[t][0] = MFMA16(a, bf0, acc[t][0]);
                acc[t][1] = MFMA16(a, bf1, acc[t][1]);
            }
        }
        #pragma unroll
        for (int t = 0; t < 4; t++) {
            #pragma unroll
            for (int i = 0; i < 4; i++) {
                int row = base + t * 16 + g * 4 + i;
                if (row < n_rows) {
                    float v0 = acc[t][0][i]; v0 = v0 > 0.f ? v0 : 0.f;
                    float v1 = acc[t][1][i]; v1 = v1 > 0.f ? v1 : 0.f;
                    out[(size_t)row * 128 + c0] = (f16)v0;
                    out[(size_t)row * 128 + c1] = (f16)v1;
                }
            }
        }
    }
}

// ---------------- edge MLP: out[e] = relu([h_s|h_d|ea] @ Wm1 + bm1) . Wm2 + bm2 ----------------
#define APITCH 296
__global__ __launch_bounds__(256, 1) void k_edge(
    const f16* __restrict__ h2, const float* __restrict__ ea,
    const int* __restrict__ src, const int* __restrict__ dst,
    const f16* __restrict__ Wmf, const float* __restrict__ bm1,
    const float* __restrict__ Wm2, const float* __restrict__ bm2,
    float* __restrict__ out, int E, int iters, int gridW) {
    __shared__ __align__(16) f16 sW[9 * 8 * 64 * 8];      // 73728 B
    __shared__ __align__(16) f16 sA[2][64 * APITCH];       // 75776 B
    __shared__ float sPart[4][64];                          // 1024 B
    const int tid = threadIdx.x, lane = tid & 63, w = tid >> 6;
    const int l15 = lane & 15, g = lane >> 4;

    for (int i = tid; i < 9 * 8 * 64; i += 256)
        *(uint4*)&sW[(size_t)i * 8] = *(const uint4*)&Wmf[(size_t)i * 8];
    {
        f16* pz = &sA[0][0];
        for (int i = tid; i < 2 * 64 * APITCH / 8; i += 256) {
            f16x8 z = {};
            *(f16x8*)(pz + (size_t)i * 8) = z;
        }
    }
    __syncthreads();

    const float b0  = bm1[(2 * w) * 16 + l15];
    const float b1  = bm1[(2 * w + 1) * 16 + l15];
    const float w20 = Wm2[(2 * w) * 16 + l15];
    const float w21 = Wm2[(2 * w + 1) * 16 + l15];
    const float bv  = bm2[0];
    const int sr = lane >> 2, sq = lane & 3;

    uint4 hs[4], hd[4];
    union { f16 h[4]; uint2 u; } eu;

    auto stage_load = [&](int ebase) {
        int er = ebase + w * 16 + sr;
        if (er > E - 1) er = E - 1;
        const int is = src[er], id = dst[er];
        const uint4* ps = (const uint4*)(h2 + (size_t)is * 128);
        const uint4* pd = (const uint4*)(h2 + (size_t)id * 128);
        #pragma unroll
        for (int i = 0; i < 4; i++) { hs[i] = ps[sq + 4 * i]; hd[i] = pd[sq + 4 * i]; }
        float4 ev = *(const float4*)(ea + (size_t)er * 16 + sq * 4);
        eu.h[0] = (f16)ev.x; eu.h[1] = (f16)ev.y; eu.h[2] = (f16)ev.z; eu.h[3] = (f16)ev.w;
    };
    auto stage_write = [&](f16* buf) {
        f16* rowp = buf + (w * 16 + sr) * APITCH;
        #pragma unroll
        for (int i = 0; i < 4; i++) {
            *(uint4*)(rowp +       (sq + 4 * i) * 8) = hs[i];
            *(uint4*)(rowp + 128 + (sq + 4 * i) * 8) = hd[i];
        }
        *(uint2*)(rowp + 256 + sq * 4) = eu.u;
    };

    stage_load(blockIdx.x * 64);
    stage_write(&sA[0][0]);
    __syncthreads();

    int cur = 0;
    for (int it = 0; it < iters; ++it) {
        const int ebase = (blockIdx.x + it * gridW) * 64;
        if (ebase >= E) break;
        const int nxt = (blockIdx.x + (it + 1) * gridW) * 64;
        const bool has_next = (it + 1 < iters) && (nxt < E);
        if (has_next) stage_load(nxt);   // global loads in flight under MFMAs

        f32x4 acc[4][2];
        #pragma unroll
        for (int t = 0; t < 4; t++) {
            acc[t][0] = f32x4{b0, b0, b0, b0};
            acc[t][1] = f32x4{b1, b1, b1, b1};
        }
        const f16* Ab = &sA[cur][0];
        #pragma unroll
        for (int s = 0; s < 9; s++) {
            f16x8 bf0 = *(const f16x8*)&sW[((s * 8 + 2 * w    ) * 64 + lane) * 8];
            f16x8 bf1 = *(const f16x8*)&sW[((s * 8 + 2 * w + 1) * 64 + lane) * 8];
            const int koff = s * 32 + g * 8;
            #pragma unroll
            for (int t = 0; t < 4; t++) {
                f16x8 a = *(const f16x8*)(Ab + (t * 16 + l15) * APITCH + koff);
                acc[t][0] = MFMA16(a, bf0, acc[t][0]);
                acc[t][1] = MFMA16(a, bf1, acc[t][1]);
            }
        }
        #pragma unroll
        for (int t = 0; t < 4; t++) {
            float p[4];
            #pragma unroll
            for (int i = 0; i < 4; i++) {
                float v0 = acc[t][0][i]; v0 = v0 > 0.f ? v0 : 0.f;
                float v1 = acc[t][1][i]; v1 = v1 > 0.f ? v1 : 0.f;
                p[i] = v0 * w20 + v1 * w21;
            }
            #pragma unroll
            for (int m = 1; m < 16; m <<= 1) {
                #pragma unroll
                for (int i = 0; i < 4; i++) p[i] += __shfl_xor(p[i], m, 64);
            }
            if (l15 == 0) {
                #pragma unroll
                for (int i = 0; i < 4; i++) sPart[w][t * 16 + g * 4 + i] = p[i];
            }
        }
        __syncthreads();
        if (tid < 64) {
            int e = ebase + tid;
            if (e < E)
                out[e] = sPart[0][tid] + sPart[1][tid] + sPart[2][tid] + sPart[3][tid] + bv;
        }
        if (has_next) stage_write(&sA[cur ^ 1][0]);
        __syncthreads();
        cur ^= 1;
    }
}

// ---------------- host launch ----------------
extern "C" void kernel_launch(void* const* d_in, const int* in_sizes, int n_in,
                              void* d_out, int out_size, void* d_ws, size_t ws_size,
                              hipStream_t stream) {
    const float* x   = (const float*)d_in[0];
    const void*  ei  = d_in[1];
    const float* ea  = (const float*)d_in[2];
    const float* Wl1 = (const float*)d_in[3];
    const float* Wr1 = (const float*)d_in[4];
    const float* b1  = (const float*)d_in[5];
    const float* Wl2 = (const float*)d_in[6];
    const float* Wr2 = (const float*)d_in[7];
    const float* b2  = (const float*)d_in[8];
    const float* Wm1 = (const float*)d_in[9];
    const float* bm1 = (const float*)d_in[10];
    const float* Wm2 = (const float*)d_in[11];
    const float* bm2 = (const float*)d_in[12];

    const int N = in_sizes[0] / 128;
    const int E = in_sizes[1] / 2;

    char* ws = (char*)d_ws;
    size_t off = 0;
    auto alloc = [&](size_t bytes) -> void* {
        void* p = ws + off;
        off = (off + bytes + 255) & ~(size_t)255;
        return p;
    };
    f16* xh     = (f16*)alloc((size_t)N * 128 * 2);   // also reused as h2
    f16* mean   = (f16*)alloc((size_t)N * 128 * 2);
    f16* h1     = (f16*)alloc((size_t)N * 128 * 2);
    int* src    = (int*)alloc((size_t)E * 4);
    int* dst    = (int*)alloc((size_t)E * 4);
    int* col    = (int*)alloc((size_t)E * 4);
    int* deg    = (int*)alloc((size_t)N * 4);
    int* rowptr = (int*)alloc((size_t)(N + 1) * 4);
    int* cursor = (int*)alloc((size_t)N * 4);
    f16* w1f    = (f16*)alloc((size_t)8 * 8 * 64 * 8 * 2);
    f16* w2f    = (f16*)alloc((size_t)8 * 8 * 64 * 8 * 2);
    f16* wmf    = (f16*)alloc((size_t)9 * 8 * 64 * 8 * 2);
    int* flag   = (int*)alloc(4);
    if (off > ws_size) return;   // workspace too small: bail (will fail validation loudly)
    f16* h2 = xh;

    const int eb = (E + 255) / 256;

    k_detect<<<1, 64, 0, stream>>>((const long long*)ei, N, flag);
    k_idx<<<eb, 256, 0, stream>>>(ei, E, flag, src, dst);
    k_x2h<<<(N * 128 / 8 + 255) / 256, 256, 0, stream>>>(x, xh, N * 128);
    k_wfrag<<<16, 256, 0, stream>>>(Wl1, Wr1, w1f, 8);
    k_wfrag<<<16, 256, 0, stream>>>(Wl2, Wr2, w2f, 8);
    k_wfrag<<<18, 256, 0, stream>>>(Wm1, nullptr, wmf, 9);

    hipMemsetAsync(deg, 0, (size_t)N * 4, stream);
    k_hist<<<eb, 256, 0, stream>>>(dst, E, deg);
    k_scan<<<1, 1024, 0, stream>>>(deg, N, rowptr, cursor);
    k_scatter<<<eb, 256, 0, stream>>>(src, dst, E, cursor, col);

    const int gridW = 250;
    const int rb = (N + 63) / 64;
    const int g_iters = (rb + gridW - 1) / gridW;

    k_agg<<<(N + 3) / 4, 256, 0, stream>>>(xh, rowptr, col, mean, N);
    k_gemm_sage<<<gridW, 256, 0, stream>>>(mean, xh, w1f, b1, h1, N, g_iters, gridW);
    k_agg<<<(N + 3) / 4, 256, 0, stream>>>(h1, rowptr, col, mean, N);
    k_gemm_sage<<<gridW, 256, 0, stream>>>(mean, h1, w2f, b2, h2, N, g_iters, gridW);

    const int nb = (E + 63) / 64;
    const int e_iters = (nb + gridW - 1) / gridW;
    k_edge<<<gridW, 256, 0, stream>>>(h2, ea, src, dst, wmf, bm1, Wm2, bm2,
                                      (float*)d_out, E, e_iters, gridW);
}

// Round 2
// 758.564 us; speedup vs baseline: 1.3544x; 1.3544x over previous
//
#include <hip/hip_runtime.h>

typedef _Float16 f16;
typedef _Float16 f16x8 __attribute__((ext_vector_type(8)));
typedef float f32x4 __attribute__((ext_vector_type(4)));

#define MFMA16(a,b,c) __builtin_amdgcn_mfma_f32_16x16x32_f16((a),(b),(c),0,0,0)

// ---------------- index dtype detection + normalization ----------------
__global__ void k_detect(const long long* ei, int n_nodes, int* flag) {
    if (blockIdx.x == 0 && threadIdx.x == 0) {
        int ok = 1;
        for (int i = 0; i < 64; i++) {
            long long v = ei[i];
            if (v < 0 || v >= n_nodes) { ok = 0; break; }
        }
        *flag = ok;   // 1 => buffer is int64, 0 => int32
    }
}

__global__ void k_idx(const void* ei, int E, const int* __restrict__ flag,
                      int* __restrict__ src, int* __restrict__ dst) {
    int e = blockIdx.x * 256 + threadIdx.x;
    if (e >= E) return;
    if (*flag) {
        const long long* p = (const long long*)ei;
        src[e] = (int)p[e];
        dst[e] = (int)p[(size_t)E + e];
    } else {
        const int* p = (const int*)ei;
        src[e] = p[e];
        dst[e] = p[(size_t)E + e];
    }
}

// ---------------- fp32 -> fp16 convert (x table) ----------------
__global__ void k_x2h(const float* __restrict__ x, f16* __restrict__ xh, int n) {
    int i = (blockIdx.x * 256 + threadIdx.x) * 8;
    if (i >= n) return;
    float4 a = *(const float4*)(x + i);
    float4 b = *(const float4*)(x + i + 4);
    f16x8 h;
    h[0] = (f16)a.x; h[1] = (f16)a.y; h[2] = (f16)a.z; h[3] = (f16)a.w;
    h[4] = (f16)b.x; h[5] = (f16)b.y; h[6] = (f16)b.z; h[7] = (f16)b.w;
    *(f16x8*)(xh + i) = h;
}

// ---------------- SAGE W -> fp16 frag-ordered ----------------
__global__ void k_wfrag(const float* __restrict__ Wa, const float* __restrict__ Wb,
                        f16* __restrict__ dst, int KS) {
    int t = blockIdx.x * 256 + threadIdx.x;
    int total = KS * 8 * 64;
    if (t >= total) return;
    int l = t & 63;
    int s = t >> 9;
    int k0 = s * 32 + (l >> 4) * 8;
    int j = ((t >> 6) & 7) * 16 + (l & 15);
    f16x8 h;
    #pragma unroll
    for (int e = 0; e < 8; e++) {
        int k = k0 + e;
        float v = (k < 128) ? Wa[k * 128 + j] : Wb[(k - 128) * 128 + j];
        h[e] = (f16)v;
    }
    *(f16x8*)(dst + (size_t)t * 8) = h;
}

// ---------------- z-GEMM W frags: B[k][j], K=128, 256 cols ----------------
// frag id: ((s*16 + c)*64 + lane)*8 + e ; k = s*32+(lane>>4)*8+e ; j = c*16+(lane&15)
// j<128 -> Wm1[k][j] (W1s) ; j>=128 -> Wm1[128+k][j-128] (W1d)
__global__ void k_zfrag(const float* __restrict__ Wm1, f16* __restrict__ dst) {
    int t = blockIdx.x * 256 + threadIdx.x;
    if (t >= 4 * 16 * 64) return;
    int lane = t & 63, c = (t >> 6) & 15, s = t >> 10;
    int k0 = s * 32 + (lane >> 4) * 8;
    int j = c * 16 + (lane & 15);
    f16x8 h;
    #pragma unroll
    for (int e = 0; e < 8; e++) {
        int k = k0 + e;
        float v = (j < 128) ? Wm1[k * 128 + j] : Wm1[(128 + k) * 128 + (j - 128)];
        h[e] = (f16)v;
    }
    *(f16x8*)(dst + (size_t)t * 8) = h;
}

// ---------------- edge-attr W frags (W1e = Wm1 rows 256..271), K padded to 32 ----------------
__global__ void k_wefrag(const float* __restrict__ Wm1, f16* __restrict__ dst) {
    int t = blockIdx.x * 256 + threadIdx.x;
    if (t >= 8 * 64) return;
    int lane = t & 63, ct = t >> 6;
    int k0 = (lane >> 4) * 8;
    int j = ct * 16 + (lane & 15);
    f16x8 h;
    #pragma unroll
    for (int e = 0; e < 8; e++) {
        int k = k0 + e;
        h[e] = (k < 16) ? (f16)Wm1[(256 + k) * 128 + j] : (f16)0.0f;
    }
    *(f16x8*)(dst + (size_t)t * 8) = h;
}

// ---------------- CSR build ----------------
__global__ void k_hist(const int* __restrict__ dst, int E, int* __restrict__ deg) {
    int e = blockIdx.x * 256 + threadIdx.x;
    if (e < E) atomicAdd(&deg[dst[e]], 1);
}

__global__ void k_scan(const int* __restrict__ deg, int n,
                       int* __restrict__ rowptr, int* __restrict__ cursor) {
    __shared__ int wsum[16];
    const int tid = threadIdx.x, lane = tid & 63, wid = tid >> 6;
    int carry = 0;
    for (int base = 0; base < n; base += 4096) {
        int i = base + tid * 4;
        int d0 = (i     < n) ? deg[i]     : 0;
        int d1 = (i + 1 < n) ? deg[i + 1] : 0;
        int d2 = (i + 2 < n) ? deg[i + 2] : 0;
        int d3 = (i + 3 < n) ? deg[i + 3] : 0;
        int s = d0 + d1 + d2 + d3;
        int inc = s;
        #pragma unroll
        for (int off = 1; off < 64; off <<= 1) {
            int u = __shfl_up(inc, off, 64);
            if (lane >= off) inc += u;
        }
        if (lane == 63) wsum[wid] = inc;
        __syncthreads();
        if (tid < 16) {
            int v = wsum[tid];
            #pragma unroll
            for (int off = 1; off < 16; off <<= 1) {
                int u = __shfl_up(v, off, 64);
                if (tid >= off) v += u;
            }
            wsum[tid] = v;
        }
        __syncthreads();
        int woff = (wid == 0) ? 0 : wsum[wid - 1];
        int excl = carry + woff + (inc - s);
        int e1 = excl + d0, e2 = e1 + d1, e3 = e2 + d2;
        if (i     < n) { rowptr[i]     = excl; cursor[i]     = excl; }
        if (i + 1 < n) { rowptr[i + 1] = e1;   cursor[i + 1] = e1; }
        if (i + 2 < n) { rowptr[i + 2] = e2;   cursor[i + 2] = e2; }
        if (i + 3 < n) { rowptr[i + 3] = e3;   cursor[i + 3] = e3; }
        carry += wsum[15];
        __syncthreads();
    }
    if (tid == 0) rowptr[n] = carry;
}

__global__ void k_scatter(const int* __restrict__ src, const int* __restrict__ dst, int E,
                          int* __restrict__ cursor, int* __restrict__ col) {
    int e = blockIdx.x * 256 + threadIdx.x;
    if (e < E) {
        int p = atomicAdd(&cursor[dst[e]], 1);
        col[p] = src[e];
    }
}

// ---------------- mean aggregation: one wave per node ----------------
__global__ void k_agg(const f16* __restrict__ tab, const int* __restrict__ rowptr,
                      const int* __restrict__ col, f16* __restrict__ mean, int n_nodes) {
    const int gw = (int)((blockIdx.x * (unsigned)blockDim.x + threadIdx.x) >> 6);
    const int lane = threadIdx.x & 63;
    if (gw >= n_nodes) return;
    const int s0 = rowptr[gw], s1 = rowptr[gw + 1];
    float a0 = 0.f, a1 = 0.f;
    int k = s0;
    for (; k + 1 < s1; k += 2) {
        const int n0 = col[k], n1 = col[k + 1];
        union { unsigned int u; f16 h[2]; } u0, u1;
        u0.u = *(const unsigned int*)(tab + (size_t)n0 * 128 + lane * 2);
        u1.u = *(const unsigned int*)(tab + (size_t)n1 * 128 + lane * 2);
        a0 += (float)u0.h[0] + (float)u1.h[0];
        a1 += (float)u0.h[1] + (float)u1.h[1];
    }
    if (k < s1) {
        const int n0 = col[k];
        union { unsigned int u; f16 h[2]; } u0;
        u0.u = *(const unsigned int*)(tab + (size_t)n0 * 128 + lane * 2);
        a0 += (float)u0.h[0];
        a1 += (float)u0.h[1];
    }
    int d = s1 - s0; if (d < 1) d = 1;
    const float inv = 1.f / (float)d;
    union { unsigned int u; f16 h[2]; } r;
    r.h[0] = (f16)(a0 * inv);
    r.h[1] = (f16)(a1 * inv);
    *(unsigned int*)(mean + (size_t)gw * 128 + lane * 2) = r.u;
}

// ---------------- SAGE GEMM: h = relu([A1|A2] @ W + b) ----------------
__global__ __launch_bounds__(256, 2) void k_gemm_sage(
    const f16* __restrict__ A1, const f16* __restrict__ A2,
    const f16* __restrict__ Wf, const float* __restrict__ bias,
    f16* __restrict__ out, int n_rows, int iters, int gridW) {
    __shared__ __align__(16) f16 sW[8 * 8 * 64 * 8];
    const int tid = threadIdx.x, lane = tid & 63, w = tid >> 6;
    const int l15 = lane & 15, g = lane >> 4;
    for (int i = tid; i < 8 * 8 * 64; i += 256)
        *(uint4*)&sW[(size_t)i * 8] = *(const uint4*)&Wf[(size_t)i * 8];
    __syncthreads();
    const int c0 = (2 * w) * 16 + l15, c1 = (2 * w + 1) * 16 + l15;
    const float b0 = bias[c0], b1 = bias[c1];
    for (int it = 0; it < iters; ++it) {
        const int base = (blockIdx.x + it * gridW) * 64;
        if (base >= n_rows) break;
        f32x4 acc[4][2];
        #pragma unroll
        for (int t = 0; t < 4; t++) {
            acc[t][0] = f32x4{b0, b0, b0, b0};
            acc[t][1] = f32x4{b1, b1, b1, b1};
        }
        #pragma unroll
        for (int s = 0; s < 8; s++) {
            const f16* Asrc = (s < 4) ? A1 : A2;
            const int koff = (s & 3) * 32 + g * 8;
            f16x8 bf0 = *(const f16x8*)&sW[((s * 8 + 2 * w    ) * 64 + lane) * 8];
            f16x8 bf1 = *(const f16x8*)&sW[((s * 8 + 2 * w + 1) * 64 + lane) * 8];
            #pragma unroll
            for (int t = 0; t < 4; t++) {
                int row = base + t * 16 + l15;
                if (row >= n_rows) row = n_rows - 1;
                f16x8 a = *(const f16x8*)(Asrc + (size_t)row * 128 + koff);
                acc[t][0] = MFMA16(a, bf0, acc[t][0]);
                acc[t][1] = MFMA16(a, bf1, acc[t][1]);
            }
        }
        #pragma unroll
        for (int t = 0; t < 4; t++) {
            #pragma unroll
            for (int i = 0; i < 4; i++) {
                int row = base + t * 16 + g * 4 + i;
                if (row < n_rows) {
                    float v0 = acc[t][0][i]; v0 = v0 > 0.f ? v0 : 0.f;
                    float v1 = acc[t][1][i]; v1 = v1 > 0.f ? v1 : 0.f;
                    out[(size_t)row * 128 + c0] = (f16)v0;
                    out[(size_t)row * 128 + c1] = (f16)v1;
                }
            }
        }
    }
}

// ---------------- z-GEMM: z[v] = [h2 @ W1s | h2 @ W1d + bm1], fp16 out ----------------
__global__ __launch_bounds__(256, 2) void k_zgemm(
    const f16* __restrict__ h2, const f16* __restrict__ zwf,
    const float* __restrict__ bm1, f16* __restrict__ z,
    int n_rows, int iters, int gridW) {
    const int tid = threadIdx.x, lane = tid & 63, w = tid >> 6;
    const int l15 = lane & 15, g = lane >> 4;
    f16x8 wf[4][4];
    #pragma unroll
    for (int s = 0; s < 4; s++)
        #pragma unroll
        for (int cc = 0; cc < 4; cc++)
            wf[s][cc] = *(const f16x8*)(zwf + ((size_t)((s * 16 + 4 * w + cc) * 64 + lane)) * 8);
    float bias[4];
    #pragma unroll
    for (int cc = 0; cc < 4; cc++) {
        int j = (4 * w + cc) * 16 + l15;
        bias[cc] = (j >= 128) ? bm1[j - 128] : 0.0f;
    }
    for (int it = 0; it < iters; ++it) {
        const int base = (blockIdx.x + it * gridW) * 64;
        if (base >= n_rows) break;
        f32x4 acc[4][4];
        #pragma unroll
        for (int t = 0; t < 4; t++)
            #pragma unroll
            for (int cc = 0; cc < 4; cc++)
                acc[t][cc] = f32x4{bias[cc], bias[cc], bias[cc], bias[cc]};
        #pragma unroll
        for (int s = 0; s < 4; s++) {
            f16x8 a[4];
            #pragma unroll
            for (int t = 0; t < 4; t++) {
                int row = base + t * 16 + l15;
                if (row >= n_rows) row = n_rows - 1;
                a[t] = *(const f16x8*)(h2 + (size_t)row * 128 + s * 32 + g * 8);
            }
            #pragma unroll
            for (int cc = 0; cc < 4; cc++)
                #pragma unroll
                for (int t = 0; t < 4; t++)
                    acc[t][cc] = MFMA16(a[t], wf[s][cc], acc[t][cc]);
        }
        #pragma unroll
        for (int t = 0; t < 4; t++)
            #pragma unroll
            for (int cc = 0; cc < 4; cc++)
                #pragma unroll
                for (int i = 0; i < 4; i++) {
                    int row = base + t * 16 + g * 4 + i;
                    if (row < n_rows)
                        z[(size_t)row * 256 + (4 * w + cc) * 16 + l15] = (f16)acc[t][cc][i];
                }
    }
}

// ---------------- edge kernel v2 ----------------
// out[e] = Wm2 . relu(z_s[src[e]] + z_d[dst[e]] + ea[e] @ W1e) + bm2
#define ZP 136   // zsum LDS pitch (halfs); 272 B row = 16B-aligned, reads 2-way free
__global__ __launch_bounds__(256, 3) void k_edge2(
    const f16* __restrict__ z, const float* __restrict__ ea,
    const int* __restrict__ src, const int* __restrict__ dst,
    const f16* __restrict__ wef, const float* __restrict__ Wm2,
    const float* __restrict__ bm2, float* __restrict__ out,
    int E, int iters, int gridW) {
    __shared__ __align__(16) f16 sZ[2][64 * ZP];       // 34816 B
    __shared__ __align__(16) f16 sEA[2][4 * 64 * 8];   // 8192 B, MFMA-frag order
    __shared__ float sPart[4][64];                      // 1024 B
    const int tid = threadIdx.x, lane = tid & 63, w = tid >> 6;
    const int l15 = lane & 15, g = lane >> 4;
    const int sr = lane >> 2, sq = lane & 3;
    const int slot_s = w * 16 + sr;

    // zero-init sEA (covers the k>=16 zero-pad region that staging never writes)
    for (int i = tid; i < 2 * 4 * 64; i += 256)
        *(f16x8*)(&sEA[0][0] + (size_t)i * 8) = f16x8{};

    const f16x8 be0 = *(const f16x8*)(wef + ((size_t)((2 * w) * 64 + lane)) * 8);
    const f16x8 be1 = *(const f16x8*)(wef + ((size_t)((2 * w + 1) * 64 + lane)) * 8);
    const float w20 = Wm2[(2 * w) * 16 + l15];
    const float w21 = Wm2[(2 * w + 1) * 16 + l15];
    const float bv = bm2[0];

    f16x8 zs[4], zd[4];
    union { f16 h[4]; uint2 u2; } eh;

    auto stage_load = [&](int ebase) {
        int er = ebase + slot_s; if (er > E - 1) er = E - 1;
        const int is = src[er], id = dst[er];
        const f16* ps = z + (size_t)is * 256 + sq * 32;
        const f16* pd = z + (size_t)id * 256 + 128 + sq * 32;
        #pragma unroll
        for (int i = 0; i < 4; i++) {
            zs[i] = *(const f16x8*)(ps + i * 8);
            zd[i] = *(const f16x8*)(pd + i * 8);
        }
        float4 ev = *(const float4*)(ea + (size_t)er * 16 + sq * 4);
        eh.h[0] = (f16)ev.x; eh.h[1] = (f16)ev.y; eh.h[2] = (f16)ev.z; eh.h[3] = (f16)ev.w;
    };
    auto stage_write = [&](int buf) {
        f16* zp = &sZ[buf][0] + slot_s * ZP + sq * 32;
        #pragma unroll
        for (int i = 0; i < 4; i++) {
            f16x8 v = zs[i] + zd[i];            // v_pk_add_f16
            *(f16x8*)(zp + i * 8) = v;
        }
        // ea -> frag order: element (slot, k=sq*4..sq*4+3) -> [t=slot>>4][lane=(sq>>1)*16+(slot&15)][e=(sq&1)*4+..]
        f16* ep = &sEA[buf][0] +
                  ((size_t)((slot_s >> 4) * 64 + (sq >> 1) * 16 + (slot_s & 15)) * 8 + (sq & 1) * 4);
        *(uint2*)ep = eh.u2;
    };

    stage_load(blockIdx.x * 64);
    __syncthreads();            // zero-init visible before first stage_write
    stage_write(0);
    __syncthreads();

    int cur = 0;
    for (int it = 0; it < iters; ++it) {
        const int ebase = (blockIdx.x + it * gridW) * 64;
        if (ebase >= E) break;
        const int nxt = (blockIdx.x + (it + 1) * gridW) * 64;
        const bool has_next = (it + 1 < iters) && (nxt < E);
        if (has_next) stage_load(nxt);   // global gathers in flight under compute

        f32x4 acc[4][2];
        #pragma unroll
        for (int t = 0; t < 4; t++) { acc[t][0] = f32x4{0,0,0,0}; acc[t][1] = f32x4{0,0,0,0}; }
        const f16* EAb = &sEA[cur][0];
        #pragma unroll
        for (int t = 0; t < 4; t++) {
            f16x8 a = *(const f16x8*)(EAb + ((size_t)(t * 64 + lane)) * 8);
            acc[t][0] = MFMA16(a, be0, acc[t][0]);
            acc[t][1] = MFMA16(a, be1, acc[t][1]);
        }
        const f16* Zb = &sZ[cur][0];
        #pragma unroll
        for (int t = 0; t < 4; t++) {
            float p[4];
            #pragma unroll
            for (int i = 0; i < 4; i++) {
                int slot = t * 16 + g * 4 + i;
                float z0 = (float)Zb[slot * ZP + (2 * w) * 16 + l15];
                float z1 = (float)Zb[slot * ZP + (2 * w + 1) * 16 + l15];
                float v0 = z0 + acc[t][0][i]; v0 = v0 > 0.f ? v0 : 0.f;
                float v1 = z1 + acc[t][1][i]; v1 = v1 > 0.f ? v1 : 0.f;
                p[i] = v0 * w20 + v1 * w21;
            }
            #pragma unroll
            for (int m = 1; m < 16; m <<= 1)
                #pragma unroll
                for (int i = 0; i < 4; i++) p[i] += __shfl_xor(p[i], m, 64);
            if (l15 == 0)
                #pragma unroll
                for (int i = 0; i < 4; i++) sPart[w][t * 16 + g * 4 + i] = p[i];
        }
        __syncthreads();
        if (tid < 64) {
            int e = ebase + tid;
            if (e < E)
                out[e] = sPart[0][tid] + sPart[1][tid] + sPart[2][tid] + sPart[3][tid] + bv;
        }
        if (has_next) stage_write(cur ^ 1);
        __syncthreads();
        cur ^= 1;
    }
}

// ---------------- host launch ----------------
extern "C" void kernel_launch(void* const* d_in, const int* in_sizes, int n_in,
                              void* d_out, int out_size, void* d_ws, size_t ws_size,
                              hipStream_t stream) {
    const float* x   = (const float*)d_in[0];
    const void*  ei  = d_in[1];
    const float* ea  = (const float*)d_in[2];
    const float* Wl1 = (const float*)d_in[3];
    const float* Wr1 = (const float*)d_in[4];
    const float* b1  = (const float*)d_in[5];
    const float* Wl2 = (const float*)d_in[6];
    const float* Wr2 = (const float*)d_in[7];
    const float* b2  = (const float*)d_in[8];
    const float* Wm1 = (const float*)d_in[9];
    const float* bm1 = (const float*)d_in[10];
    const float* Wm2 = (const float*)d_in[11];
    const float* bm2 = (const float*)d_in[12];

    const int N = in_sizes[0] / 128;
    const int E = in_sizes[1] / 2;

    char* ws = (char*)d_ws;
    size_t off = 0;
    auto alloc = [&](size_t bytes) -> void* {
        void* p = ws + off;
        off = (off + bytes + 255) & ~(size_t)255;
        return p;
    };
    f16* xh     = (f16*)alloc((size_t)N * 128 * 2);   // reused as h2 (layer-2 out)
    f16* mean   = (f16*)alloc((size_t)N * 128 * 2);   // z table aliases mean+h1 later
    f16* h1     = (f16*)alloc((size_t)N * 128 * 2);
    int* src    = (int*)alloc((size_t)E * 4);
    int* dst    = (int*)alloc((size_t)E * 4);
    int* col    = (int*)alloc((size_t)E * 4);
    int* deg    = (int*)alloc((size_t)N * 4);
    int* rowptr = (int*)alloc((size_t)(N + 1) * 4);
    int* cursor = (int*)alloc((size_t)N * 4);
    f16* w1f    = (f16*)alloc((size_t)8 * 8 * 64 * 8 * 2);
    f16* w2f    = (f16*)alloc((size_t)8 * 8 * 64 * 8 * 2);
    f16* zwf    = (f16*)alloc((size_t)4 * 16 * 64 * 8 * 2);
    f16* wef    = (f16*)alloc((size_t)8 * 64 * 8 * 2);
    int* flag   = (int*)alloc(4);
    if (off > ws_size) return;
    f16* h2 = xh;
    f16* z  = mean;   // [N][256] fp16 = N*512 B <= mean(N*256B)+h1(N*256B) region

    const int eb = (E + 255) / 256;

    k_detect<<<1, 64, 0, stream>>>((const long long*)ei, N, flag);
    k_idx<<<eb, 256, 0, stream>>>(ei, E, flag, src, dst);
    k_x2h<<<(N * 128 / 8 + 255) / 256, 256, 0, stream>>>(x, xh, N * 128);
    k_wfrag<<<16, 256, 0, stream>>>(Wl1, Wr1, w1f, 8);
    k_wfrag<<<16, 256, 0, stream>>>(Wl2, Wr2, w2f, 8);
    k_zfrag<<<16, 256, 0, stream>>>(Wm1, zwf);
    k_wefrag<<<2, 256, 0, stream>>>(Wm1, wef);

    hipMemsetAsync(deg, 0, (size_t)N * 4, stream);
    k_hist<<<eb, 256, 0, stream>>>(dst, E, deg);
    k_scan<<<1, 1024, 0, stream>>>(deg, N, rowptr, cursor);
    k_scatter<<<eb, 256, 0, stream>>>(src, dst, E, cursor, col);

    const int gridW = 250;
    const int rb = (N + 63) / 64;
    const int g_iters = (rb + gridW - 1) / gridW;

    k_agg<<<(N + 3) / 4, 256, 0, stream>>>(xh, rowptr, col, mean, N);
    k_gemm_sage<<<gridW, 256, 0, stream>>>(mean, xh, w1f, b1, h1, N, g_iters, gridW);
    k_agg<<<(N + 3) / 4, 256, 0, stream>>>(h1, rowptr, col, mean, N);
    k_gemm_sage<<<gridW, 256, 0, stream>>>(mean, h1, w2f, b2, h2, N, g_iters, gridW);

    // z precompute AFTER gemm2 (z aliases mean+h1, both dead now)
    const int zg = 512;
    const int z_iters = (rb + zg - 1) / zg;
    k_zgemm<<<zg, 256, 0, stream>>>(h2, zwf, bm1, z, N, z_iters, zg);

    const int eg = 768;
    const int nb = (E + 63) / 64;
    const int e_iters = (nb + eg - 1) / eg;
    k_edge2<<<eg, 256, 0, stream>>>(z, ea, src, dst, wef, Wm2, bm2,
                                    (float*)d_out, E, e_iters, eg);
}

// Round 3
// 602.777 us; speedup vs baseline: 1.7044x; 1.2584x over previous
//
#include <hip/hip_runtime.h>

typedef _Float16 f16;
typedef _Float16 f16x8 __attribute__((ext_vector_type(8)));
typedef float f32x4 __attribute__((ext_vector_type(4)));

#define MFMA16(a,b,c) __builtin_amdgcn_mfma_f32_16x16x32_f16((a),(b),(c),0,0,0)

// ---------------- index dtype detection + normalization ----------------
__global__ void k_detect(const long long* ei, int n_nodes, int* flag) {
    if (blockIdx.x == 0 && threadIdx.x == 0) {
        int ok = 1;
        for (int i = 0; i < 64; i++) {
            long long v = ei[i];
            if (v < 0 || v >= n_nodes) { ok = 0; break; }
        }
        *flag = ok;   // 1 => buffer is int64, 0 => int32
    }
}

__global__ void k_idx(const void* ei, int E, const int* __restrict__ flag,
                      int* __restrict__ src, int* __restrict__ dst) {
    int e = blockIdx.x * 256 + threadIdx.x;
    if (e >= E) return;
    if (*flag) {
        const long long* p = (const long long*)ei;
        src[e] = (int)p[e];
        dst[e] = (int)p[(size_t)E + e];
    } else {
        const int* p = (const int*)ei;
        src[e] = p[e];
        dst[e] = p[(size_t)E + e];
    }
}

// ---------------- fp32 -> fp16 convert (x table) ----------------
__global__ void k_x2h(const float* __restrict__ x, f16* __restrict__ xh, int n) {
    int i = (blockIdx.x * 256 + threadIdx.x) * 8;
    if (i >= n) return;
    float4 a = *(const float4*)(x + i);
    float4 b = *(const float4*)(x + i + 4);
    f16x8 h;
    h[0] = (f16)a.x; h[1] = (f16)a.y; h[2] = (f16)a.z; h[3] = (f16)a.w;
    h[4] = (f16)b.x; h[5] = (f16)b.y; h[6] = (f16)b.z; h[7] = (f16)b.w;
    *(f16x8*)(xh + i) = h;
}

// ---------------- SAGE W -> fp16 frag-ordered ----------------
__global__ void k_wfrag(const float* __restrict__ Wa, const float* __restrict__ Wb,
                        f16* __restrict__ dst, int KS) {
    int t = blockIdx.x * 256 + threadIdx.x;
    int total = KS * 8 * 64;
    if (t >= total) return;
    int l = t & 63;
    int s = t >> 9;
    int k0 = s * 32 + (l >> 4) * 8;
    int j = ((t >> 6) & 7) * 16 + (l & 15);
    f16x8 h;
    #pragma unroll
    for (int e = 0; e < 8; e++) {
        int k = k0 + e;
        float v = (k < 128) ? Wa[k * 128 + j] : Wb[(k - 128) * 128 + j];
        h[e] = (f16)v;
    }
    *(f16x8*)(dst + (size_t)t * 8) = h;
}

// ---------------- z-GEMM W frags ----------------
__global__ void k_zfrag(const float* __restrict__ Wm1, f16* __restrict__ dst) {
    int t = blockIdx.x * 256 + threadIdx.x;
    if (t >= 4 * 16 * 64) return;
    int lane = t & 63, c = (t >> 6) & 15, s = t >> 10;
    int k0 = s * 32 + (lane >> 4) * 8;
    int j = c * 16 + (lane & 15);
    f16x8 h;
    #pragma unroll
    for (int e = 0; e < 8; e++) {
        int k = k0 + e;
        float v = (j < 128) ? Wm1[k * 128 + j] : Wm1[(128 + k) * 128 + (j - 128)];
        h[e] = (f16)v;
    }
    *(f16x8*)(dst + (size_t)t * 8) = h;
}

// ---------------- edge-attr W frags (W1e = Wm1 rows 256..271), K padded to 32 ----------------
__global__ void k_wefrag(const float* __restrict__ Wm1, f16* __restrict__ dst) {
    int t = blockIdx.x * 256 + threadIdx.x;
    if (t >= 8 * 64) return;
    int lane = t & 63, ct = t >> 6;
    int k0 = (lane >> 4) * 8;
    int j = ct * 16 + (lane & 15);
    f16x8 h;
    #pragma unroll
    for (int e = 0; e < 8; e++) {
        int k = k0 + e;
        h[e] = (k < 16) ? (f16)Wm1[(256 + k) * 128 + j] : (f16)0.0f;
    }
    *(f16x8*)(dst + (size_t)t * 8) = h;
}

// ---------------- CSR build ----------------
__global__ void k_hist(const int* __restrict__ dst, int E, int* __restrict__ deg) {
    int e = blockIdx.x * 256 + threadIdx.x;
    if (e < E) atomicAdd(&deg[dst[e]], 1);
}

// 3-pass multi-block scan (replaces serial single-block k_scan)
__global__ void k_bsum(const int* __restrict__ deg, int n, int* __restrict__ bsum) {
    __shared__ int ws[4];
    const int tid = threadIdx.x;
    int i = blockIdx.x * 1024 + tid * 4;
    int s = 0;
    if (i + 3 < n) {
        int4 d = *(const int4*)(deg + i);
        s = d.x + d.y + d.z + d.w;
    } else {
        #pragma unroll
        for (int j = 0; j < 4; j++) if (i + j < n) s += deg[i + j];
    }
    #pragma unroll
    for (int m = 1; m < 64; m <<= 1) s += __shfl_xor(s, m, 64);
    if ((tid & 63) == 0) ws[tid >> 6] = s;
    __syncthreads();
    if (tid == 0) bsum[blockIdx.x] = ws[0] + ws[1] + ws[2] + ws[3];
}

__global__ void k_bscan(int* __restrict__ bsum, int nb, int* __restrict__ rowptr_n) {
    // 256 threads, nb <= 256
    __shared__ int wsum[4];
    const int tid = threadIdx.x, lane = tid & 63, wid = tid >> 6;
    int v = (tid < nb) ? bsum[tid] : 0;
    int inc = v;
    #pragma unroll
    for (int off = 1; off < 64; off <<= 1) {
        int u = __shfl_up(inc, off, 64);
        if (lane >= off) inc += u;
    }
    if (lane == 63) wsum[wid] = inc;
    __syncthreads();
    int woff = 0;
    for (int j = 0; j < wid; j++) woff += wsum[j];
    int excl = woff + inc - v;
    if (tid < nb) bsum[tid] = excl;
    if (tid == nb - 1) rowptr_n[0] = excl + v;   // total edges -> rowptr[n]
}

__global__ void k_rowptr(const int* __restrict__ deg, int n, const int* __restrict__ boff,
                         int* __restrict__ rowptr, int* __restrict__ cursor) {
    __shared__ int wsum[4];
    const int tid = threadIdx.x, lane = tid & 63, wid = tid >> 6;
    int i = blockIdx.x * 1024 + tid * 4;
    int d0 = 0, d1 = 0, d2 = 0, d3 = 0;
    if (i + 3 < n) {
        int4 d = *(const int4*)(deg + i);
        d0 = d.x; d1 = d.y; d2 = d.z; d3 = d.w;
    } else {
        if (i     < n) d0 = deg[i];
        if (i + 1 < n) d1 = deg[i + 1];
        if (i + 2 < n) d2 = deg[i + 2];
        if (i + 3 < n) d3 = deg[i + 3];
    }
    int s = d0 + d1 + d2 + d3;
    int inc = s;
    #pragma unroll
    for (int off = 1; off < 64; off <<= 1) {
        int u = __shfl_up(inc, off, 64);
        if (lane >= off) inc += u;
    }
    if (lane == 63) wsum[wid] = inc;
    __syncthreads();
    int woff = 0;
    for (int j = 0; j < wid; j++) woff += wsum[j];
    int excl = boff[blockIdx.x] + woff + inc - s;
    int e1 = excl + d0, e2 = e1 + d1, e3 = e2 + d2;
    if (i     < n) { rowptr[i]     = excl; cursor[i]     = excl; }
    if (i + 1 < n) { rowptr[i + 1] = e1;   cursor[i + 1] = e1; }
    if (i + 2 < n) { rowptr[i + 2] = e2;   cursor[i + 2] = e2; }
    if (i + 3 < n) { rowptr[i + 3] = e3;   cursor[i + 3] = e3; }
}

__global__ void k_scatter(const int* __restrict__ src, const int* __restrict__ dst, int E,
                          int* __restrict__ cursor, int* __restrict__ col) {
    int e = blockIdx.x * 256 + threadIdx.x;
    if (e < E) {
        int p = atomicAdd(&cursor[dst[e]], 1);
        col[p] = src[e];
    }
}

// ---------------- mean aggregation: one wave per node, 4 groups x 16 lanes x 16B ----------------
// group g (lane>>4) owns neighbors k = s0+g, s0+g+4, ...; lane covers halfs (lane&15)*8..+8
__global__ __launch_bounds__(256) void k_agg(
    const f16* __restrict__ tab, const int* __restrict__ rowptr,
    const int* __restrict__ col, f16* __restrict__ mean, int n_nodes) {
    const int gw = (int)((blockIdx.x * (unsigned)blockDim.x + threadIdx.x) >> 6);
    const int lane = threadIdx.x & 63;
    if (gw >= n_nodes) return;
    const int g = lane >> 4, c = lane & 15;
    const int s0 = rowptr[gw], s1 = rowptr[gw + 1];
    float acc[8] = {0.f, 0.f, 0.f, 0.f, 0.f, 0.f, 0.f, 0.f};
    int k = s0 + g;
    for (; k + 4 < s1; k += 8) {            // 2 rows per group in flight (8 per wave)
        const int n0 = col[k], n1 = col[k + 4];
        f16x8 v0 = *(const f16x8*)(tab + (size_t)n0 * 128 + c * 8);
        f16x8 v1 = *(const f16x8*)(tab + (size_t)n1 * 128 + c * 8);
        #pragma unroll
        for (int j = 0; j < 8; j++) acc[j] += (float)v0[j] + (float)v1[j];
    }
    if (k < s1) {
        const int n0 = col[k];
        f16x8 v0 = *(const f16x8*)(tab + (size_t)n0 * 128 + c * 8);
        #pragma unroll
        for (int j = 0; j < 8; j++) acc[j] += (float)v0[j];
    }
    // reduce across the 4 groups (lanes differing in bits 4,5)
    #pragma unroll
    for (int j = 0; j < 8; j++) {
        acc[j] += __shfl_xor(acc[j], 16, 64);
        acc[j] += __shfl_xor(acc[j], 32, 64);
    }
    int d = s1 - s0; if (d < 1) d = 1;
    const float inv = 1.f / (float)d;
    if (g == 0) {
        f16x8 r;
        #pragma unroll
        for (int j = 0; j < 8; j++) r[j] = (f16)(acc[j] * inv);
        *(f16x8*)(mean + (size_t)gw * 128 + c * 8) = r;
    }
}

// ---------------- SAGE GEMM: h = relu([A1|A2] @ W + b) ----------------
__global__ __launch_bounds__(256, 2) void k_gemm_sage(
    const f16* __restrict__ A1, const f16* __restrict__ A2,
    const f16* __restrict__ Wf, const float* __restrict__ bias,
    f16* __restrict__ out, int n_rows, int iters, int gridW) {
    __shared__ __align__(16) f16 sW[8 * 8 * 64 * 8];
    const int tid = threadIdx.x, lane = tid & 63, w = tid >> 6;
    const int l15 = lane & 15, g = lane >> 4;
    for (int i = tid; i < 8 * 8 * 64; i += 256)
        *(uint4*)&sW[(size_t)i * 8] = *(const uint4*)&Wf[(size_t)i * 8];
    __syncthreads();
    const int c0 = (2 * w) * 16 + l15, c1 = (2 * w + 1) * 16 + l15;
    const float b0 = bias[c0], b1 = bias[c1];
    for (int it = 0; it < iters; ++it) {
        const int base = (blockIdx.x + it * gridW) * 64;
        if (base >= n_rows) break;
        f32x4 acc[4][2];
        #pragma unroll
        for (int t = 0; t < 4; t++) {
            acc[t][0] = f32x4{b0, b0, b0, b0};
            acc[t][1] = f32x4{b1, b1, b1, b1};
        }
        #pragma unroll
        for (int s = 0; s < 8; s++) {
            const f16* Asrc = (s < 4) ? A1 : A2;
            const int koff = (s & 3) * 32 + g * 8;
            f16x8 bf0 = *(const f16x8*)&sW[((s * 8 + 2 * w    ) * 64 + lane) * 8];
            f16x8 bf1 = *(const f16x8*)&sW[((s * 8 + 2 * w + 1) * 64 + lane) * 8];
            #pragma unroll
            for (int t = 0; t < 4; t++) {
                int row = base + t * 16 + l15;
                if (row >= n_rows) row = n_rows - 1;
                f16x8 a = *(const f16x8*)(Asrc + (size_t)row * 128 + koff);
                acc[t][0] = MFMA16(a, bf0, acc[t][0]);
                acc[t][1] = MFMA16(a, bf1, acc[t][1]);
            }
        }
        #pragma unroll
        for (int t = 0; t < 4; t++) {
            #pragma unroll
            for (int i = 0; i < 4; i++) {
                int row = base + t * 16 + g * 4 + i;
                if (row < n_rows) {
                    float v0 = acc[t][0][i]; v0 = v0 > 0.f ? v0 : 0.f;
                    float v1 = acc[t][1][i]; v1 = v1 > 0.f ? v1 : 0.f;
                    out[(size_t)row * 128 + c0] = (f16)v0;
                    out[(size_t)row * 128 + c1] = (f16)v1;
                }
            }
        }
    }
}

// ---------------- z-GEMM: z[v] = [h2 @ W1s | h2 @ W1d + bm1], fp16 out ----------------
__global__ __launch_bounds__(256, 2) void k_zgemm(
    const f16* __restrict__ h2, const f16* __restrict__ zwf,
    const float* __restrict__ bm1, f16* __restrict__ z,
    int n_rows, int iters, int gridW) {
    const int tid = threadIdx.x, lane = tid & 63, w = tid >> 6;
    const int l15 = lane & 15, g = lane >> 4;
    f16x8 wf[4][4];
    #pragma unroll
    for (int s = 0; s < 4; s++)
        #pragma unroll
        for (int cc = 0; cc < 4; cc++)
            wf[s][cc] = *(const f16x8*)(zwf + ((size_t)((s * 16 + 4 * w + cc) * 64 + lane)) * 8);
    float bias[4];
    #pragma unroll
    for (int cc = 0; cc < 4; cc++) {
        int j = (4 * w + cc) * 16 + l15;
        bias[cc] = (j >= 128) ? bm1[j - 128] : 0.0f;
    }
    for (int it = 0; it < iters; ++it) {
        const int base = (blockIdx.x + it * gridW) * 64;
        if (base >= n_rows) break;
        f32x4 acc[4][4];
        #pragma unroll
        for (int t = 0; t < 4; t++)
            #pragma unroll
            for (int cc = 0; cc < 4; cc++)
                acc[t][cc] = f32x4{bias[cc], bias[cc], bias[cc], bias[cc]};
        #pragma unroll
        for (int s = 0; s < 4; s++) {
            f16x8 a[4];
            #pragma unroll
            for (int t = 0; t < 4; t++) {
                int row = base + t * 16 + l15;
                if (row >= n_rows) row = n_rows - 1;
                a[t] = *(const f16x8*)(h2 + (size_t)row * 128 + s * 32 + g * 8);
            }
            #pragma unroll
            for (int cc = 0; cc < 4; cc++)
                #pragma unroll
                for (int t = 0; t < 4; t++)
                    acc[t][cc] = MFMA16(a[t], wf[s][cc], acc[t][cc]);
        }
        #pragma unroll
        for (int t = 0; t < 4; t++)
            #pragma unroll
            for (int cc = 0; cc < 4; cc++)
                #pragma unroll
                for (int i = 0; i < 4; i++) {
                    int row = base + t * 16 + g * 4 + i;
                    if (row < n_rows)
                        z[(size_t)row * 256 + (4 * w + cc) * 16 + l15] = (f16)acc[t][cc][i];
                }
    }
}

// ---------------- edge kernel v3: single-buffered LDS, register-held prefetch ----------------
// out[e] = Wm2 . relu(z_s[src[e]] + z_d[dst[e]] + ea[e] @ W1e) + bm2
#define ZP 136
__global__ __launch_bounds__(256, 4) void k_edge2(
    const f16* __restrict__ z, const float* __restrict__ ea,
    const int* __restrict__ src, const int* __restrict__ dst,
    const f16* __restrict__ wef, const float* __restrict__ Wm2,
    const float* __restrict__ bm2, float* __restrict__ out,
    int E, int iters, int gridW) {
    __shared__ __align__(16) f16 sZ[64 * ZP];        // 17408 B
    __shared__ __align__(16) f16 sEA[4 * 64 * 8];    // 4096 B, MFMA-frag order
    __shared__ float sPart[4][64];                    // 1024 B  -> 22.5 KB total, 4+ blocks/CU
    const int tid = threadIdx.x, lane = tid & 63, w = tid >> 6;
    const int l15 = lane & 15, g = lane >> 4;
    const int sr = lane >> 2, sq = lane & 3;
    const int slot_s = w * 16 + sr;

    // zero-init sEA once (k>=16 zero-pad region is never re-written)
    for (int i = tid; i < 4 * 64; i += 256)
        *(f16x8*)(&sEA[0] + (size_t)i * 8) = f16x8{};

    const f16x8 be0 = *(const f16x8*)(wef + ((size_t)((2 * w) * 64 + lane)) * 8);
    const f16x8 be1 = *(const f16x8*)(wef + ((size_t)((2 * w + 1) * 64 + lane)) * 8);
    const float w20 = Wm2[(2 * w) * 16 + l15];
    const float w21 = Wm2[(2 * w + 1) * 16 + l15];
    const float bv = bm2[0];

    f16x8 zs[4], zd[4];
    union { f16 h[4]; uint2 u2; } eh;

    auto stage_load = [&](int ebase) {
        int er = ebase + slot_s; if (er > E - 1) er = E - 1;
        const int is = src[er], id = dst[er];
        const f16* ps = z + (size_t)is * 256 + sq * 32;
        const f16* pd = z + (size_t)id * 256 + 128 + sq * 32;
        #pragma unroll
        for (int i = 0; i < 4; i++) {
            zs[i] = *(const f16x8*)(ps + i * 8);
            zd[i] = *(const f16x8*)(pd + i * 8);
        }
        float4 ev = *(const float4*)(ea + (size_t)er * 16 + sq * 4);
        eh.h[0] = (f16)ev.x; eh.h[1] = (f16)ev.y; eh.h[2] = (f16)ev.z; eh.h[3] = (f16)ev.w;
    };
    auto stage_write = [&]() {
        f16* zp = &sZ[0] + slot_s * ZP + sq * 32;
        #pragma unroll
        for (int i = 0; i < 4; i++) {
            f16x8 v = zs[i] + zd[i];            // v_pk_add_f16
            *(f16x8*)(zp + i * 8) = v;
        }
        f16* ep = &sEA[0] +
                  ((size_t)((slot_s >> 4) * 64 + (sq >> 1) * 16 + (slot_s & 15)) * 8 + (sq & 1) * 4);
        *(uint2*)ep = eh.u2;
    };

    stage_load(blockIdx.x * 64);
    __syncthreads();            // zero-init of sEA visible before first stage_write
    stage_write();
    __syncthreads();

    for (int it = 0; it < iters; ++it) {
        const int ebase = (blockIdx.x + it * gridW) * 64;
        if (ebase >= E) break;
        const int nxt = (blockIdx.x + (it + 1) * gridW) * 64;
        const bool has_next = (it + 1 < iters) && (nxt < E);
        if (has_next) stage_load(nxt);   // gathers for next tile in flight under compute

        f32x4 acc[4][2];
        #pragma unroll
        for (int t = 0; t < 4; t++) { acc[t][0] = f32x4{0,0,0,0}; acc[t][1] = f32x4{0,0,0,0}; }
        #pragma unroll
        for (int t = 0; t < 4; t++) {
            f16x8 a = *(const f16x8*)(&sEA[0] + ((size_t)(t * 64 + lane)) * 8);
            acc[t][0] = MFMA16(a, be0, acc[t][0]);
            acc[t][1] = MFMA16(a, be1, acc[t][1]);
        }
        #pragma unroll
        for (int t = 0; t < 4; t++) {
            float p[4];
            #pragma unroll
            for (int i = 0; i < 4; i++) {
                int slot = t * 16 + g * 4 + i;
                float z0 = (float)sZ[slot * ZP + (2 * w) * 16 + l15];
                float z1 = (float)sZ[slot * ZP + (2 * w + 1) * 16 + l15];
                float v0 = z0 + acc[t][0][i]; v0 = v0 > 0.f ? v0 : 0.f;
                float v1 = z1 + acc[t][1][i]; v1 = v1 > 0.f ? v1 : 0.f;
                p[i] = v0 * w20 + v1 * w21;
            }
            #pragma unroll
            for (int m = 1; m < 16; m <<= 1)
                #pragma unroll
                for (int i = 0; i < 4; i++) p[i] += __shfl_xor(p[i], m, 64);
            if (l15 == 0)
                #pragma unroll
                for (int i = 0; i < 4; i++) sPart[w][t * 16 + g * 4 + i] = p[i];
        }
        __syncthreads();                 // sZ/sEA reads done; sPart ready
        if (tid < 64) {
            int e = ebase + tid;
            if (e < E)
                out[e] = sPart[0][tid] + sPart[1][tid] + sPart[2][tid] + sPart[3][tid] + bv;
        }
        if (has_next) stage_write();     // overwrite sZ/sEA with next tile
        __syncthreads();
    }
}

// ---------------- host launch ----------------
extern "C" void kernel_launch(void* const* d_in, const int* in_sizes, int n_in,
                              void* d_out, int out_size, void* d_ws, size_t ws_size,
                              hipStream_t stream) {
    const float* x   = (const float*)d_in[0];
    const void*  ei  = d_in[1];
    const float* ea  = (const float*)d_in[2];
    const float* Wl1 = (const float*)d_in[3];
    const float* Wr1 = (const float*)d_in[4];
    const float* b1  = (const float*)d_in[5];
    const float* Wl2 = (const float*)d_in[6];
    const float* Wr2 = (const float*)d_in[7];
    const float* b2  = (const float*)d_in[8];
    const float* Wm1 = (const float*)d_in[9];
    const float* bm1 = (const float*)d_in[10];
    const float* Wm2 = (const float*)d_in[11];
    const float* bm2 = (const float*)d_in[12];

    const int N = in_sizes[0] / 128;
    const int E = in_sizes[1] / 2;

    char* ws = (char*)d_ws;
    size_t off = 0;
    auto alloc = [&](size_t bytes) -> void* {
        void* p = ws + off;
        off = (off + bytes + 255) & ~(size_t)255;
        return p;
    };
    f16* xh     = (f16*)alloc((size_t)N * 128 * 2);   // reused as h2 (layer-2 out)
    f16* mean   = (f16*)alloc((size_t)N * 128 * 2);   // z table aliases mean+h1 later
    f16* h1     = (f16*)alloc((size_t)N * 128 * 2);
    int* src    = (int*)alloc((size_t)E * 4);
    int* dst    = (int*)alloc((size_t)E * 4);
    int* col    = (int*)alloc((size_t)E * 4);
    int* deg    = (int*)alloc((size_t)N * 4);
    int* rowptr = (int*)alloc((size_t)(N + 1) * 4);
    int* cursor = (int*)alloc((size_t)N * 4);
    int* bsum   = (int*)alloc((size_t)1024 * 4);
    f16* w1f    = (f16*)alloc((size_t)8 * 8 * 64 * 8 * 2);
    f16* w2f    = (f16*)alloc((size_t)8 * 8 * 64 * 8 * 2);
    f16* zwf    = (f16*)alloc((size_t)4 * 16 * 64 * 8 * 2);
    f16* wef    = (f16*)alloc((size_t)8 * 64 * 8 * 2);
    int* flag   = (int*)alloc(4);
    if (off > ws_size) return;
    f16* h2 = xh;
    f16* z  = mean;   // [N][256] fp16 occupies mean+h1 region

    const int eb = (E + 255) / 256;
    const int nbk = (N + 1023) / 1024;   // scan blocks (<=256 for N<=262144)

    k_detect<<<1, 64, 0, stream>>>((const long long*)ei, N, flag);
    k_idx<<<eb, 256, 0, stream>>>(ei, E, flag, src, dst);
    k_x2h<<<(N * 128 / 8 + 255) / 256, 256, 0, stream>>>(x, xh, N * 128);
    k_wfrag<<<16, 256, 0, stream>>>(Wl1, Wr1, w1f, 8);
    k_wfrag<<<16, 256, 0, stream>>>(Wl2, Wr2, w2f, 8);
    k_zfrag<<<16, 256, 0, stream>>>(Wm1, zwf);
    k_wefrag<<<2, 256, 0, stream>>>(Wm1, wef);

    hipMemsetAsync(deg, 0, (size_t)N * 4, stream);
    k_hist<<<eb, 256, 0, stream>>>(dst, E, deg);
    k_bsum<<<nbk, 256, 0, stream>>>(deg, N, bsum);
    k_bscan<<<1, 256, 0, stream>>>(bsum, nbk, rowptr + N);
    k_rowptr<<<nbk, 256, 0, stream>>>(deg, N, bsum, rowptr, cursor);
    k_scatter<<<eb, 256, 0, stream>>>(src, dst, E, cursor, col);

    const int gridW = 512;
    const int rb = (N + 63) / 64;
    const int g_iters = (rb + gridW - 1) / gridW;

    k_agg<<<(N + 3) / 4, 256, 0, stream>>>(xh, rowptr, col, mean, N);
    k_gemm_sage<<<gridW, 256, 0, stream>>>(mean, xh, w1f, b1, h1, N, g_iters, gridW);
    k_agg<<<(N + 3) / 4, 256, 0, stream>>>(h1, rowptr, col, mean, N);
    k_gemm_sage<<<gridW, 256, 0, stream>>>(mean, h1, w2f, b2, h2, N, g_iters, gridW);

    // z precompute AFTER gemm2 (z aliases mean+h1, both dead now)
    const int zg = 512;
    const int z_iters = (rb + zg - 1) / zg;
    k_zgemm<<<zg, 256, 0, stream>>>(h2, zwf, bm1, z, N, z_iters, zg);

    const int eg = 1280;
    const int nb = (E + 63) / 64;
    const int e_iters = (nb + eg - 1) / eg;
    k_edge2<<<eg, 256, 0, stream>>>(z, ea, src, dst, wef, Wm2, bm2,
                                    (float*)d_out, E, e_iters, eg);
}